// Round 9
// baseline (3749.247 us; speedup 1.0000x reference)
//
#include <hip/hip_runtime.h>

#define NG 8      // independent batch groups (16 rows each)

// Two monotonic counters per group, 128 B apart: [g*64]=cntA (layer1, 8
// arrivals/step), [g*64+32]=cntB (layer2, 4/step). Zeroed by init_kernel
// (stream-ordered before the main kernel) every launch.
__device__ __attribute__((aligned(128))) unsigned int g_cnt[NG * 64];

typedef __attribute__((ext_vector_type(8))) short short8;
typedef __attribute__((ext_vector_type(4))) float floatx4;

// Split fp32 v into bf16 hi + bf16 lo (residual), packed (hi<<16)|lo.
__device__ __forceinline__ unsigned int split_pack(float v) {
    unsigned int u  = __float_as_uint(v);
    unsigned int hb = u & 0xffff0000u;          // truncated-bf16 hi, exact in fp32
    float r = v - __uint_as_float(hb);          // exact residual
    return hb | (__float_as_uint(r) >> 16);
}

__device__ __forceinline__ float sigmoidf_(float z) {
    return 1.0f / (1.0f + __expf(-z));
}

// ---- r4-proven device-coherent primitives (no new asm) ----
// sc1 stores write through to the coherence point (L2 never dirtied => the
// release arrival's wbl2 is ~free). sc1 u64 loads fetch from L3 (never
// stale). Relaxed RMW spin executes memory-side at L3 (never stale, no
// per-poll cache maintenance). No acquire fence anywhere => weights/x stay
// L1/L2-warm across all 512 steps.
__device__ __forceinline__ void st_coh(unsigned int* p, unsigned int v) {
    __hip_atomic_store(p, v, __ATOMIC_RELAXED, __HIP_MEMORY_SCOPE_AGENT);
}
__device__ __forceinline__ unsigned long long ld_coh64(const unsigned long long* p) {
    return __hip_atomic_load(p, __ATOMIC_RELAXED, __HIP_MEMORY_SCOPE_AGENT);
}
__device__ __forceinline__ unsigned int ld_rmw(unsigned int* p) {
    return __hip_atomic_fetch_add(p, 0u, __ATOMIC_RELAXED, __HIP_MEMORY_SCOPE_AGENT);
}
__device__ __forceinline__ void arrive(unsigned int* cnt) {
    __hip_atomic_fetch_add(cnt, 1u, __ATOMIC_RELEASE, __HIP_MEMORY_SCOPE_AGENT);
}
// Dual spin: both RMWs issued back-to-back each iteration -> one L3 round
// trip covers both counters.
__device__ __forceinline__ void spin2(unsigned int* ca, unsigned int ta,
                                      unsigned int* cb, unsigned int tb) {
    for (;;) {
        unsigned int ra = ld_rmw(ca);
        unsigned int rb = ld_rmw(cb);
        if (ra >= ta && rb >= tb) return;
    }
}

// Unpack 4 u64 (8 packed hi/lo uints, register-resident) into bf16 hi/lo
// MFMA fragments. u64 index j holds uints [2j, 2j+1] (little-endian).
__device__ __forceinline__ void unpack_q(const unsigned long long* q, short8& ah, short8& al) {
#pragma unroll
    for (int j = 0; j < 4; ++j) {
        unsigned int lo = (unsigned int)q[j];
        unsigned int hi = (unsigned int)(q[j] >> 32);
        ah[2 * j]     = (short)(lo >> 16);
        al[2 * j]     = (short)(lo & 0xffffu);
        ah[2 * j + 1] = (short)(hi >> 16);
        al[2 * j + 1] = (short)(hi & 0xffffu);
    }
}

__device__ __forceinline__ void cvt_x(const float* xp, short8& ah, short8& al) {
    float4 xa = *(const float4*)(xp);
    float4 xb = *(const float4*)(xp + 4);
    float xv[8] = {xa.x, xa.y, xa.z, xa.w, xb.x, xb.y, xb.z, xb.w};
#pragma unroll
    for (int j = 0; j < 8; ++j) {
        unsigned int u  = __float_as_uint(xv[j]);
        unsigned int hb = u & 0xffff0000u;
        float r = xv[j] - __uint_as_float(hb);
        ah[j] = (short)(u >> 16);
        al[j] = (short)(__float_as_uint(r) >> 16);
    }
}

// One LSTM layer role for one batch group (16 rows). Wave owns the group's
// m-tile x 2 column-tiles (8 units, all 4 gates). Weights pre-split to bf16
// hi/lo MFMA B-fragments in registers.
// MFMA 16x16x32_bf16: A: m=lane&15,k=quad*8+j ; D: col=lane&15, row=quad*4+r
//
// Round-9 data path: NO LDS staging. After the gate, each lane issues ALL its
// h-fragment sc1 u64 loads up-front (one L3 RTT, 32-48 outstanding) straight
// into registers, then consumes them per-kc (compiler inserts fine-grained
// vmcnt waits => early kc compute overlaps late load returns). This deletes
// the stage->LDS->barrier->read leg and its bank conflicts from the critical
// path. (r3's per-kc load-use serialization -- 10 sequential RTTs -- was the
// earlier failure mode; issuing everything up-front is the fix.)
// The L1 x-part (kc<2) is computed BEFORE the gate (cache-resident inputs).
//
// Split-counter dependency schedule (r4-proven; init arrivals = step -1):
//   L1@s : wait cntA>=8(s+1) [peers' h1[s-1]] and (s>=2) cntB>=4s [h1-slot
//          free: L2 done s-2];  arrival at end => cntA=8(s+2)
//   L2@s : wait cntA>=8(s+2) [h1[s] ready] and cntB>=4(s+1) [peers' h2[s-1]
//          + slot free];        arrival at end => cntB=4(s+2)
template<int NKC, int KX, int GW, int UU, bool L1>
__device__ void lstm_role(const float* __restrict__ x,
                          const float* __restrict__ Wm, const float* __restrict__ Um,
                          const float* __restrict__ bias,
                          unsigned int* __restrict__ h1pk, unsigned int* __restrict__ h2pk,
                          float* __restrict__ out,
                          unsigned int* __restrict__ cntA, unsigned int* __restrict__ cntB,
                          int m0, int wid, float (*zex)[17])
{
    const int tid  = threadIdx.x;
    const int lane = tid & 63;
    const int n    = lane & 15;
    const int quad = lane >> 4;
    const int gate = n >> 2;
    const int u0   = wid * 8;             // 8 units per wave (2 coltiles x 4)
    const int arow = m0 + n;              // A-fragment row this lane loads
    const int b_l  = lane >> 2;           // epilogue: batch-local 0..15
    const int ul   = lane & 3;            // epilogue: unit-local 0..3

    // ---- one-time: weight B-fragments (hi/lo split), bias ----
    short8 bh[2][NKC], bl[2][NKC];
    float bias_v[2];
#pragma unroll
    for (int c = 0; c < 2; ++c) {
        const int col = gate * UU + u0 + c * 4 + (n & 3);
        bias_v[c] = bias[col];
#pragma unroll
        for (int kc = 0; kc < NKC; ++kc) {
#pragma unroll
            for (int j = 0; j < 8; ++j) {
                int k = kc * 32 + quad * 8 + j;
                float w = (k < KX) ? Wm[k * GW + col] : Um[(k - KX) * GW + col];
                unsigned int p = split_pack(w);
                bh[c][kc][j] = (short)(p >> 16);
                bl[c][kc][j] = (short)(p & 0xffffu);
            }
        }
    }

    // ---- zero the "step -1" h slice this wave owns (ws is poisoned) ----
#pragma unroll
    for (int c = 0; c < 2; ++c) {
        if (L1) st_coh(&h1pk[32768 + (m0 + b_l) * 256 + u0 + c * 4 + ul], 0u);
        else    st_coh(&h2pk[16384 + (m0 + b_l) * 128 + u0 + c * 4 + ul], 0u);
    }
    float cst[2] = {0.f, 0.f};

    __syncthreads();                      // drains each wave's zero stores
    if (tid == 0) arrive(L1 ? cntA : cntB);

    for (int s = 0; s < 512; ++s) {
        // ---- pre-gate: acc init + L1 x-part (cache-resident, no recurrent
        // dependency) off the post-observe critical path ----
        floatx4 acc[2];
#pragma unroll
        for (int c = 0; c < 2; ++c)
            acc[c] = {bias_v[c], bias_v[c], bias_v[c], bias_v[c]};
        if (L1) {
            const float* xsrc = x + (size_t)arow * (512 * 64) + s * 64;
#pragma unroll
            for (int kc = 0; kc < 2; ++kc) {
                short8 ah, al;
                cvt_x(xsrc + kc * 32 + quad * 8, ah, al);
#pragma unroll
                for (int c = 0; c < 2; ++c) {
                    acc[c] = __builtin_amdgcn_mfma_f32_16x16x32_bf16(ah, bh[c][kc], acc[c], 0, 0, 0);
                    acc[c] = __builtin_amdgcn_mfma_f32_16x16x32_bf16(ah, bl[c][kc], acc[c], 0, 0, 0);
                    acc[c] = __builtin_amdgcn_mfma_f32_16x16x32_bf16(al, bh[c][kc], acc[c], 0, 0, 0);
                }
            }
        }

        // ---- wait for inputs (thread 0 spins, barrier publishes to block) ----
        if (tid == 0) {
            if (L1) spin2(cntA, 8u * (s + 1), cntB, (s >= 2) ? 4u * (unsigned)s : 0u);
            else    spin2(cntA, 8u * (s + 2), cntB, 4u * (s + 1));
        }
        __syncthreads();

        // ---- issue ALL h-fragment loads up-front (one L3 RTT) ----
        const int NHA = L1 ? 8 : 8;                       // kc-chunks from h1
        const unsigned long long* hA64 = (const unsigned long long*)
            (L1 ? (h1pk + ((s + 1) & 1) * 32768 + arow * 256)     // h1[s-1]
                : (h1pk + (s & 1) * 32768 + arow * 256));         // h1[s]
        unsigned long long qa[8][4];
#pragma unroll
        for (int kc = 0; kc < 8; ++kc)
#pragma unroll
            for (int j = 0; j < 4; ++j)
                qa[kc][j] = ld_coh64(hA64 + kc * 16 + quad * 4 + j);

        unsigned long long qb[4][4];
        if (!L1) {
            const unsigned long long* hB64 = (const unsigned long long*)
                (h2pk + ((s + 1) & 1) * 16384 + arow * 128);      // h2[s-1]
#pragma unroll
            for (int kc = 0; kc < 4; ++kc)
#pragma unroll
                for (int j = 0; j < 4; ++j)
                    qb[kc][j] = ld_coh64(hB64 + kc * 16 + quad * 4 + j);
        }
        (void)NHA;

        // ---- recurrent MFMAs (consume register fragments per-kc) ----
#pragma unroll
        for (int kc = (L1 ? 2 : 0); kc < NKC; ++kc) {
            short8 ah, al;
            if (L1)           unpack_q(qa[kc - 2], ah, al);
            else if (kc < 8)  unpack_q(qa[kc], ah, al);
            else              unpack_q(qb[kc - 8], ah, al);
#pragma unroll
            for (int c = 0; c < 2; ++c) {
                acc[c] = __builtin_amdgcn_mfma_f32_16x16x32_bf16(ah, bh[c][kc], acc[c], 0, 0, 0);
                acc[c] = __builtin_amdgcn_mfma_f32_16x16x32_bf16(ah, bl[c][kc], acc[c], 0, 0, 0);
                acc[c] = __builtin_amdgcn_mfma_f32_16x16x32_bf16(al, bh[c][kc], acc[c], 0, 0, 0);
            }
        }

        // ---- epilogue: per coltile, gate-gather via per-wave LDS tile.
        // Wave-level lgkmcnt(0) drains the ds_writes of ALL lanes of this
        // wave before any lane's read; memory clobber stops reordering. ----
#pragma unroll
        for (int c = 0; c < 2; ++c) {
#pragma unroll
            for (int r = 0; r < 4; ++r) zex[quad * 4 + r][n] = acc[c][r];
            asm volatile("s_waitcnt lgkmcnt(0)" ::: "memory");
            float zi = zex[b_l][ 0 + ul];
            float zf = zex[b_l][ 4 + ul];
            float zg = zex[b_l][ 8 + ul];
            float zo = zex[b_l][12 + ul];
            asm volatile("s_waitcnt lgkmcnt(0)" ::: "memory");
            float ig = sigmoidf_(zi);
            float fg = sigmoidf_(zf);
            float gg = fmaxf(zg, 0.f);
            float og = sigmoidf_(zo);
            cst[c] = fg * cst[c] + ig * gg;
            float h = og * fmaxf(cst[c], 0.f);
            unsigned int p = split_pack(h);
            int b = m0 + b_l;
            if (L1) {
                st_coh(&h1pk[(s & 1) * 32768 + b * 256 + u0 + c * 4 + ul], p);
            } else {
                st_coh(&h2pk[(s & 1) * 16384 + b * 128 + u0 + c * 4 + ul], p);
                if (s == 511) out[b * 128 + u0 + c * 4 + ul] = h;
            }
        }

        // ---- publish: barrier drains all waves' sc1 stores (per-wave
        // vmcnt(0) before s_barrier), then one release arrival ----
        __syncthreads();
        if (tid == 0) arrive(L1 ? cntA : cntB);
    }
}

__global__ void __launch_bounds__(256, 1)
lstm_fused_kernel(const float* __restrict__ x,
                  const float* __restrict__ W1, const float* __restrict__ U1,
                  const float* __restrict__ b1,
                  const float* __restrict__ W2, const float* __restrict__ U2,
                  const float* __restrict__ b2,
                  float* __restrict__ out, unsigned int* __restrict__ ws)
{
    __shared__ float zex[4][16][17];       // per-wave gate-gather tiles
    unsigned int* h1pk = ws;               // [2][128][256] packed hi/lo bf16
    unsigned int* h2pk = ws + 65536;       // [2][128][128]
    const int g    = blockIdx.x & 7;       // batch group
    const int role = blockIdx.x >> 3;      // 0..7 layer1, 8..11 layer2
    const int wv   = threadIdx.x >> 6;
    const int m0   = g * 16;
    unsigned int* cntA = &g_cnt[g * 64];
    unsigned int* cntB = &g_cnt[g * 64 + 32];
    if (role < 8) {
        // layer1: 8 blocks x 4 waves = 32 unit-waves x 8 units = 256 units
        lstm_role<10, 64, 1024, 256, true >(x, W1, U1, b1, h1pk, h2pk, out,
                                            cntA, cntB, m0, role * 4 + wv, zex[wv]);
    } else {
        // layer2: 4 blocks x 4 waves = 16 unit-waves x 8 units = 128 units
        lstm_role<12, 256, 512, 128, false>(x, W2, U2, b2, h1pk, h2pk, out,
                                            cntA, cntB, m0, (role - 8) * 4 + wv, zex[wv]);
    }
}

// Pre-kernel (plain launch, cannot fail): zero barrier counters, write the
// diagnostic sentinel. Stream order publishes both to the main kernel.
// Failure signatures: absmax~7 => main never ran (launch issue);
// absmax~0.162 => main ran but produced zeros (coherence issue).
__global__ void init_kernel(float* __restrict__ out) {
    int t = blockIdx.x * 256 + threadIdx.x;
    if (t < NG * 64) g_cnt[t] = 0u;
    if (t < 16384) out[t] = 7.0f;
}

extern "C" void kernel_launch(void* const* d_in, const int* in_sizes, int n_in,
                              void* d_out, int out_size, void* d_ws, size_t ws_size,
                              hipStream_t stream) {
    const float* x  = (const float*)d_in[0];
    const float* W1 = (const float*)d_in[1];
    const float* U1 = (const float*)d_in[2];
    const float* b1 = (const float*)d_in[3];
    const float* W2 = (const float*)d_in[4];
    const float* U2 = (const float*)d_in[5];
    const float* b2 = (const float*)d_in[6];
    float* out = (float*)d_out;
    unsigned int* ws = (unsigned int*)d_ws;
    init_kernel<<<64, 256, 0, stream>>>(out);
    lstm_fused_kernel<<<96, 256, 0, stream>>>(x, W1, U1, b1, W2, U2, b2, out, ws);
}